// Round 3
// baseline (410.917 us; speedup 1.0000x reference)
//
#include <hip/hip_runtime.h>

// Problem constants
#define DIMC 192
#define HID  48          // DIM / RED
#define HW   65536       // 256*256
#define WIDTH 256
#define NPLANE 768       // B * DIM

// Native Clang vector type — required by __builtin_nontemporal_store
// (HIP's float4 is a class and is rejected). Same 16B layout.
typedef float nfloat4 __attribute__((ext_vector_type(4)));

// ---------------------------------------------------------------------------
// Per-SAMPLE pipeline: pool(b) -> conv(b), b = 0..3.
// Rationale: conv weights for sample b depend only on pooled(x_b). Running
// conv(b) immediately after pool(b) means conv re-reads a 48 MiB working set
// touched ~8 us earlier (LLC-hot, partially L2-hot: 6 MiB/XCD) instead of a
// 192 MiB set touched 33 us + 192 MiB of traffic earlier.
// ---------------------------------------------------------------------------

// ---------------------------------------------------------------------------
// Kernel 1: partial sums for one sample. Grid 768 = 192 planes x 4 strips of
// 64 rows; 256 threads. Each thread sums 16 float4. No occupancy tail
// (12 blocks/CU of 4 waves vs old 1024-thr blocks at 1.5 rounds/CU).
// pp[plane*4 + strip] = raw SUM over the strip (normalized later).
// ---------------------------------------------------------------------------
__global__ __launch_bounds__(256) void k_pool_s(const float* __restrict__ xs,
                                                float* __restrict__ pp) {
    const int plane = blockIdx.x >> 2;          // 0..191
    const int strip = blockIdx.x & 3;           // 0..3 (64 rows each)
    const float4* p = (const float4*)(xs + (size_t)plane * HW + strip * 64 * WIDTH);
    const int t = threadIdx.x;
    float s = 0.f;
#pragma unroll
    for (int k = 0; k < 16; ++k) {
        float4 v = p[k * 256 + t];
        s += (v.x + v.y) + (v.z + v.w);
    }
#pragma unroll
    for (int off = 32; off > 0; off >>= 1) s += __shfl_down(s, off, 64);
    __shared__ float wsum[4];
    const int wave = t >> 6, lane = t & 63;
    if (lane == 0) wsum[wave] = s;
    __syncthreads();
    if (t == 0) pp[blockIdx.x] = (wsum[0] + wsum[1]) + (wsum[2] + wsum[3]);
}

// ---------------------------------------------------------------------------
// Kernel 2: weight-gen prologue + 4-tap masked depthwise conv, one sample.
//   out[y][x] = w00*X[y-1][x-1] + w01*X[y-1][x] + w02*X[y-1][x+1]
//             + w10*X[y  ][x-1] + bias[c]
// Grid: 192 planes * 8 row-tiles = 1536 blocks; 4 waves x 8 rows each.
// Stores NON-TEMPORAL (write-once data; keep x resident in L2/LLC).
// ---------------------------------------------------------------------------
__global__ __launch_bounds__(256) void k_conv_s(
    const float* __restrict__ xs,       // sample base
    const float* __restrict__ pp,       // [192*4] strip sums for this sample
    const float* __restrict__ w1,       // [48,192]
    const float* __restrict__ gamma,
    const float* __restrict__ beta,
    const float* __restrict__ rmean,
    const float* __restrict__ rvar,
    const float* __restrict__ w2,       // [1728,48]
    const float* __restrict__ b2,       // [1728]
    const float* __restrict__ bias,
    float* __restrict__ outs)           // sample base
{
    const int c = blockIdx.x >> 3;              // plane within sample = channel
    const int tid = threadIdx.x;

    // ---- weight-gen prologue ----
    __shared__ float P[DIMC];
    __shared__ float T[HID];
    __shared__ float W4[4];
    if (tid < DIMC) {
        float4 v = ((const float4*)pp)[tid];    // 4 strip sums of channel tid
        P[tid] = ((v.x + v.y) + (v.z + v.w)) * (1.0f / 65536.0f);
    }
    __syncthreads();
    {
        // 48 groups of 4 lanes compute t[g] (groups never cross a wave)
        const int g = tid >> 2, l = tid & 3;
        if (g < HID) {
            const float* wr = w1 + g * DIMC;
            float acc = 0.f;
#pragma unroll 8
            for (int d = l; d < DIMC; d += 4) acc += P[d] * wr[d];
            acc += __shfl_xor(acc, 1, 64);
            acc += __shfl_xor(acc, 2, 64);
            if (l == 0) {
                const float inv = rsqrtf(rvar[g] + 1e-5f);
                float v = gamma[g] * (acc - rmean[g]) * inv + beta[g];
                T[g] = v > 0.f ? v : 0.f;
            }
        }
        __syncthreads();
        // 4 taps for this channel: rows c*9+0..3 of w2 (taps 4..8 masked)
        if (tid < 4) {
            const int o = c * 9 + tid;
            const float* wr = w2 + o * HID;
            float acc = b2[o];
#pragma unroll
            for (int j = 0; j < HID; ++j) acc += T[j] * wr[j];
            W4[tid] = acc;
        }
        __syncthreads();
    }
    const float4 wt = make_float4(W4[0], W4[1], W4[2], W4[3]); // {w00,w01,w02,w10}
    const float bs = bias[c];

    // ---- conv ----
    const int wave = tid >> 6;
    const int lane = tid & 63;
    const int y0 = ((blockIdx.x & 7) << 5) + (wave << 3);
    const float4* xp = (const float4*)(xs + (size_t)c * HW);
    nfloat4* op = (nfloat4*)(outs + (size_t)c * HW);

    float4 a;                                   // row y-1
    if (y0 == 0) a = make_float4(0.f, 0.f, 0.f, 0.f);
    else         a = xp[(y0 - 1) * 64 + lane];

#pragma unroll
    for (int r = 0; r < 8; ++r) {
        const int y = y0 + r;
        float4 bb = xp[y * 64 + lane];          // row y
        float leftA  = __shfl_up(a.w, 1, 64);   if (lane == 0)  leftA  = 0.f;
        float rightA = __shfl_down(a.x, 1, 64); if (lane == 63) rightA = 0.f;
        float leftB  = __shfl_up(bb.w, 1, 64);  if (lane == 0)  leftB  = 0.f;
        nfloat4 o;
        o.x = wt.x * leftA + wt.y * a.x + wt.z * a.y    + wt.w * leftB + bs;
        o.y = wt.x * a.x   + wt.y * a.y + wt.z * a.z    + wt.w * bb.x  + bs;
        o.z = wt.x * a.y   + wt.y * a.z + wt.z * a.w    + wt.w * bb.y  + bs;
        o.w = wt.x * a.z   + wt.y * a.w + wt.z * rightA + wt.w * bb.z  + bs;
        __builtin_nontemporal_store(o, &op[y * 64 + lane]);
        a = bb;                                 // roll: row y becomes row y-1
    }
}

// ---------------------------------------------------------------------------
extern "C" void kernel_launch(void* const* d_in, const int* in_sizes, int n_in,
                              void* d_out, int out_size, void* d_ws, size_t ws_size,
                              hipStream_t stream) {
    const float* x     = (const float*)d_in[0];
    const float* w1    = (const float*)d_in[1];
    const float* gamma = (const float*)d_in[2];
    const float* beta  = (const float*)d_in[3];
    const float* rmean = (const float*)d_in[4];
    const float* rvar  = (const float*)d_in[5];
    const float* w2    = (const float*)d_in[6];
    const float* b2    = (const float*)d_in[7];
    const float* bias  = (const float*)d_in[8];
    float* out = (float*)d_out;

    float* pp = (float*)d_ws;   // 4 * 768 floats of strip partial sums

    for (int b = 0; b < 4; ++b) {
        const float* xs = x   + (size_t)b * DIMC * HW;
        float* outs     = out + (size_t)b * DIMC * HW;
        k_pool_s<<<768, 256, 0, stream>>>(xs, pp + b * 768);
        k_conv_s<<<1536, 256, 0, stream>>>(xs, pp + b * 768, w1, gamma, beta,
                                           rmean, rvar, w2, b2, bias, outs);
    }
}